// Round 1
// baseline (11286.549 us; speedup 1.0000x reference)
//
#include <hip/hip_runtime.h>
#include <math.h>

#define NPTS 1000000
#define TWO_PI_D 6.283185307179586

// f64 weight workspace offsets (in doubles)
#define OFF_W1   0        // 128*34 = 4352
#define OFF_W2T  4352     // 128*64 = 8192 (transposed: W2T[j*64+k] = W2[k,j])
#define OFF_WS1  12544    // 128
#define OFF_BS1  12672    // 128
#define OFF_WS2T 12800    // 8192 (transposed)
#define OFF_BS2  20992    // 64
#define OFF_WF   21056    // 8192 (row-major as given)
#define OFF_BF   29248    // 128
#define OFF_WH   29376    // 18*64 = 1152
#define OFF_BH   30528    // 18
#define OFF_B1   30546    // 128
#define OFF_B2   30674    // 64
#define WD_TOTAL 30738

__global__ __launch_bounds__(256) void prep_f64(
    const float* __restrict__ W1, const float* __restrict__ b1,
    const float* __restrict__ W2, const float* __restrict__ b2,
    const float* __restrict__ Ws1, const float* __restrict__ bs1,
    const float* __restrict__ Ws2, const float* __restrict__ bs2,
    const float* __restrict__ Wf, const float* __restrict__ bf,
    const float* __restrict__ Wh, const float* __restrict__ bh,
    double* __restrict__ wd)
{
    int i = blockIdx.x * 256 + threadIdx.x;
    if (i < 4352) wd[OFF_W1 + i] = (double)W1[i];
    if (i < 8192) { int j = i >> 6, k = i & 63; wd[OFF_W2T + i] = (double)W2[k * 128 + j]; }
    if (i < 128)  wd[OFF_WS1 + i] = (double)Ws1[i];
    if (i < 128)  wd[OFF_BS1 + i] = (double)bs1[i];
    if (i < 8192) { int j = i >> 6, k = i & 63; wd[OFF_WS2T + i] = (double)Ws2[k * 128 + j]; }
    if (i < 64)   wd[OFF_BS2 + i] = (double)bs2[i];
    if (i < 8192) wd[OFF_WF + i] = (double)Wf[i];
    if (i < 128)  wd[OFF_BF + i] = (double)bf[i];
    if (i < 1152) wd[OFF_WH + i] = (double)Wh[i];
    if (i < 18)   wd[OFF_BH + i] = (double)bh[i];
    if (i < 128)  wd[OFF_B1 + i] = (double)b1[i];
    if (i < 64)   wd[OFF_B2 + i] = (double)b2[i];
}

__global__ __launch_bounds__(256) void main_f64(
    const float* __restrict__ coords, const float* __restrict__ grid,
    const double* __restrict__ wd, float* __restrict__ out)
{
    int n = blockIdx.x * 256 + threadIdx.x;
    if (n >= NPTS) return;

    const float xf = coords[3 * n + 0];
    const float yf = coords[3 * n + 1];
    const float tf = coords[3 * n + 2];

    // ---------------- bilinear interpolation (f64) ----------------
    double xi = ((double)xf + 1.0) * 0.5 * 63.0;
    double yi = ((double)yf + 1.0) * 0.5 * 63.0;
    int x0 = (int)floor(xi); x0 = x0 < 0 ? 0 : (x0 > 62 ? 62 : x0);
    int y0 = (int)floor(yi); y0 = y0 < 0 ? 0 : (y0 > 62 ? 62 : y0);
    double dx = xi - (double)x0;
    double dy = yi - (double)y0;
    double w00 = (1.0 - dx) * (1.0 - dy);
    double w01 = (1.0 - dx) * dy;          // (y1, x0)
    double w10 = dx * (1.0 - dy);          // (y0, x1)
    double w11 = dx * dy;

    const float* f00 = grid + ((size_t)y0 * 64 + x0) * 32;
    const float* f10 = f00 + 32;        // x1
    const float* f01 = f00 + 64 * 32;   // y1
    const float* f11 = f01 + 32;

    double xy[34];
    xy[0] = (double)xf;
    xy[1] = (double)yf;
#pragma unroll
    for (int i = 0; i < 32; ++i) {
        xy[2 + i] = (w00 * (double)f00[i] + w01 * (double)f01[i])
                  + (w10 * (double)f10[i] + w11 * (double)f11[i]);
    }

    // ---------------- stage A: h = relu(W1 xy + b1); h_xy = relu(W2 h + b2) ----------------
    double acc[64];   // accumulates W2 @ h, later becomes h_xy then fused
    {
        const double* b2d = wd + OFF_B2;
#pragma unroll
        for (int k = 0; k < 64; ++k) acc[k] = b2d[k];

        const double* W1d  = wd + OFF_W1;
        const double* W2Td = wd + OFF_W2T;
        const double* b1d  = wd + OFF_B1;
#pragma unroll 2
        for (int j = 0; j < 128; ++j) {
            const double* w1r = W1d + j * 34;
            double h0 = b1d[j], h1 = 0.0, h2 = 0.0, h3 = 0.0;
#pragma unroll
            for (int i = 0; i < 32; i += 4) {
                h0 = fma(xy[i + 0], w1r[i + 0], h0);
                h1 = fma(xy[i + 1], w1r[i + 1], h1);
                h2 = fma(xy[i + 2], w1r[i + 2], h2);
                h3 = fma(xy[i + 3], w1r[i + 3], h3);
            }
            h0 = fma(xy[32], w1r[32], h0);
            h1 = fma(xy[33], w1r[33], h1);
            double hj = (h0 + h2) + (h1 + h3);
            hj = fmax(hj, 0.0);
            const double* w2c = W2Td + j * 64;
#pragma unroll
            for (int k = 0; k < 64; ++k) acc[k] = fma(hj, w2c[k], acc[k]);
        }
        // acc = h_xy (already includes b2; relu:)
#pragma unroll
        for (int k = 0; k < 64; ++k) acc[k] = fmax(acc[k], 0.0);
    }

    // ---------------- stage B: SIREN t-branch ----------------
    double accT[64];  // accumulates Ws2 @ ht, later h_t
    {
        const double t = (double)tf;
        const double* bs2d = wd + OFF_BS2;
#pragma unroll
        for (int k = 0; k < 64; ++k) accT[k] = bs2d[k];

        const double* Ws1d  = wd + OFF_WS1;
        const double* bs1d  = wd + OFF_BS1;
        const double* Ws2Td = wd + OFF_WS2T;
#pragma unroll 2
        for (int j = 0; j < 128; ++j) {
            double arg = 30.0 * fma(t, Ws1d[j], bs1d[j]);
            double htj = sin(arg);
            const double* wsc = Ws2Td + j * 64;
#pragma unroll
            for (int k = 0; k < 64; ++k) accT[k] = fma(htj, wsc[k], accT[k]);
        }
#pragma unroll
        for (int k = 0; k < 64; ++k) accT[k] = sin(accT[k]);   // h_t
    }

    // ---------------- stage C: FiLM: fused = (1 + 0.1 tanh(Wf_g h_t + bf_g)) * h_xy + tanh(Wf_b h_t + bf_b) ----------------
    {
        const double* Wfd = wd + OFF_WF;
        const double* bfd = wd + OFF_BF;
#pragma unroll
        for (int k = 0; k < 64; ++k) {
            const double* wfr0 = Wfd + (size_t)k * 64;
            const double* wfr1 = Wfd + (size_t)(64 + k) * 64;
            double a0 = bfd[k],      a0b = 0.0;
            double a1 = bfd[64 + k], a1b = 0.0;
#pragma unroll
            for (int m = 0; m < 64; m += 2) {
                a0  = fma(accT[m + 0], wfr0[m + 0], a0);
                a0b = fma(accT[m + 1], wfr0[m + 1], a0b);
                a1  = fma(accT[m + 0], wfr1[m + 0], a1);
                a1b = fma(accT[m + 1], wfr1[m + 1], a1b);
            }
            double gk = tanh(a0 + a0b);
            double bk = tanh(a1 + a1b);
            double gamma = fma(0.1, gk, 1.0);
            acc[k] = fma(gamma, acc[k], bk);   // fused_k
        }
    }

    // ---------------- stage D: params = Wh fused + bh ----------------
    double p[18];
    {
        const double* Whd = wd + OFF_WH;
        const double* bhd = wd + OFF_BH;
#pragma unroll
        for (int m = 0; m < 18; ++m) {
            const double* whr = Whd + m * 64;
            double s0 = bhd[m], s1 = 0.0, s2 = 0.0, s3 = 0.0;
#pragma unroll
            for (int k = 0; k < 64; k += 4) {
                s0 = fma(acc[k + 0], whr[k + 0], s0);
                s1 = fma(acc[k + 1], whr[k + 1], s1);
                s2 = fma(acc[k + 2], whr[k + 2], s2);
                s3 = fma(acc[k + 3], whr[k + 3], s3);
            }
            p[m] = (s0 + s2) + (s1 + s3);
        }
    }

    // ---------------- final activations ----------------
    float o[18];
    {
        // softmax over p[0], p[6], p[12]
        double l0 = p[0], l1 = p[6], l2 = p[12];
        double mx = fmax(l0, fmax(l1, l2));
        double e0 = exp(l0 - mx), e1 = exp(l1 - mx), e2 = exp(l2 - mx);
        double inv = 1.0 / (e0 + e1 + e2);
        o[0]  = (float)(e0 * inv);
        o[6]  = (float)(e1 * inv);
        o[12] = (float)(e2 * inv);
#pragma unroll
        for (int kk = 0; kk < 3; ++kk) {
            double sp = p[kk * 6 + 1];
            o[kk * 6 + 1] = (float)fmax(sp, 0.0);
            double an = p[kk * 6 + 2];
            double w  = an - floor(an / TWO_PI_D) * TWO_PI_D;   // np.mod semantics
            o[kk * 6 + 2] = (float)w;
            double v1 = p[kk * 6 + 3];
            v1 = fmin(fmax(v1, -10.0), 10.0);
            o[kk * 6 + 3] = (float)exp(v1);
            double v2 = p[kk * 6 + 4];
            v2 = fmin(fmax(v2, -10.0), 10.0);
            o[kk * 6 + 4] = (float)exp(v2);
            o[kk * 6 + 5] = (float)(0.99 * tanh(p[kk * 6 + 5]));
        }
    }

    // gmm output: [N*18] at offset 0 (8B-aligned per point: 72B stride)
    float* og = out + (size_t)n * 18;
#pragma unroll
    for (int i = 0; i < 18; i += 2) {
        *reinterpret_cast<float2*>(og + i) = make_float2(o[i], o[i + 1]);
    }
    // coords passthrough at offset 18M
    float* oc = out + (size_t)18 * NPTS + (size_t)n * 3;
    oc[0] = xf; oc[1] = yf; oc[2] = tf;
}

extern "C" void kernel_launch(void* const* d_in, const int* in_sizes, int n_in,
                              void* d_out, int out_size, void* d_ws, size_t ws_size,
                              hipStream_t stream) {
    const float* coords = (const float*)d_in[0];
    const float* grid   = (const float*)d_in[1];
    const float* W1  = (const float*)d_in[2];
    const float* b1  = (const float*)d_in[3];
    const float* W2  = (const float*)d_in[4];
    const float* b2  = (const float*)d_in[5];
    const float* Ws1 = (const float*)d_in[6];
    const float* bs1 = (const float*)d_in[7];
    const float* Ws2 = (const float*)d_in[8];
    const float* bs2 = (const float*)d_in[9];
    const float* Wf  = (const float*)d_in[10];
    const float* bf  = (const float*)d_in[11];
    const float* Wh  = (const float*)d_in[12];
    const float* bh  = (const float*)d_in[13];
    double* wd = (double*)d_ws;
    float* out = (float*)d_out;

    prep_f64<<<32, 256, 0, stream>>>(W1, b1, W2, b2, Ws1, bs1, Ws2, bs2,
                                     Wf, bf, Wh, bh, wd);
    main_f64<<<(NPTS + 255) / 256, 256, 0, stream>>>(coords, grid, wd, out);
}

// Round 2
// 7954.530 us; speedup vs baseline: 1.4189x; 1.4189x over previous
//
#include <hip/hip_runtime.h>
#include <math.h>

#define NPTS 1000000
#define TWO_PI_D 6.283185307179586
#define TWO_PI_F 6.28318530717958647692f
#define TAU_BOUND 0.008f

// ---------------- workspace layout ----------------
// f64 weight area (doubles), offsets in doubles:
#define OFF_W1   0        // 128*34 = 4352
#define OFF_W2T  4352     // 8192 (W2T[j*64+k] = W2[k,j])
#define OFF_WS1  12544    // 128
#define OFF_BS1  12672    // 128
#define OFF_WS2T 12800    // 8192
#define OFF_BS2  20992    // 64
#define OFF_WF   21056    // 8192
#define OFF_BF   29248    // 128
#define OFF_WH   29376    // 1152
#define OFF_BH   30528    // 18
#define OFF_B1   30546    // 128
#define OFF_B2   30674    // 64
#define WD_DOUBLES 30738  // 245904 bytes
// byte offsets for f32/transposed + repair machinery:
#define F32T_BYTE   246016              // aligned
#define W2T32_OFF   (F32T_BYTE)             // 8192 floats
#define WS2T32_OFF  (F32T_BYTE + 32768)     // 8192 floats
#define CNT_BYTE    311552
#define LIST_BYTE   311616
#define WS_MIN_BYTES (LIST_BYTE + 65536)

// ---------------- prep: f64 copies + f32 transposes + zero counter ----------------
__global__ __launch_bounds__(256) void prep_k(
    const float* __restrict__ W1, const float* __restrict__ b1,
    const float* __restrict__ W2, const float* __restrict__ b2,
    const float* __restrict__ Ws1, const float* __restrict__ bs1,
    const float* __restrict__ Ws2, const float* __restrict__ bs2,
    const float* __restrict__ Wf, const float* __restrict__ bf,
    const float* __restrict__ Wh, const float* __restrict__ bh,
    char* __restrict__ ws)
{
    double* wd = (double*)ws;
    float* w2t32 = (float*)(ws + W2T32_OFF);
    float* ws2t32 = (float*)(ws + WS2T32_OFF);
    unsigned* cnt = (unsigned*)(ws + CNT_BYTE);
    int i = blockIdx.x * 256 + threadIdx.x;
    if (i == 0) *cnt = 0u;
    if (i < 4352) wd[OFF_W1 + i] = (double)W1[i];
    if (i < 8192) {
        int j = i >> 6, k = i & 63;
        float w2v = W2[k * 128 + j];
        float wsv = Ws2[k * 128 + j];
        wd[OFF_W2T + i] = (double)w2v;  w2t32[i] = w2v;
        wd[OFF_WS2T + i] = (double)wsv; ws2t32[i] = wsv;
    }
    if (i < 128)  wd[OFF_WS1 + i] = (double)Ws1[i];
    if (i < 128)  wd[OFF_BS1 + i] = (double)bs1[i];
    if (i < 64)   wd[OFF_BS2 + i] = (double)bs2[i];
    if (i < 8192) wd[OFF_WF + i] = (double)Wf[i];
    if (i < 128)  wd[OFF_BF + i] = (double)bf[i];
    if (i < 1152) wd[OFF_WH + i] = (double)Wh[i];
    if (i < 18)   wd[OFF_BH + i] = (double)bh[i];
    if (i < 128)  wd[OFF_B1 + i] = (double)b1[i];
    if (i < 64)   wd[OFF_B2 + i] = (double)b2[i];
}

// ---------------- exact f64 per-point evaluation (repair / fallback) ----------------
__device__ void point_f64(int n, const float* __restrict__ coords,
                          const float* __restrict__ grid,
                          const double* __restrict__ wd, float* __restrict__ out)
{
    const float xf = coords[3 * n + 0];
    const float yf = coords[3 * n + 1];
    const float tf = coords[3 * n + 2];

    double xi = ((double)xf + 1.0) * 0.5 * 63.0;
    double yi = ((double)yf + 1.0) * 0.5 * 63.0;
    int x0 = (int)floor(xi); x0 = x0 < 0 ? 0 : (x0 > 62 ? 62 : x0);
    int y0 = (int)floor(yi); y0 = y0 < 0 ? 0 : (y0 > 62 ? 62 : y0);
    double dx = xi - (double)x0;
    double dy = yi - (double)y0;
    double w00 = (1.0 - dx) * (1.0 - dy);
    double w01 = (1.0 - dx) * dy;
    double w10 = dx * (1.0 - dy);
    double w11 = dx * dy;

    const float* f00 = grid + ((size_t)y0 * 64 + x0) * 32;
    const float* f10 = f00 + 32;
    const float* f01 = f00 + 64 * 32;
    const float* f11 = f01 + 32;

    double xy[34];
    xy[0] = (double)xf;
    xy[1] = (double)yf;
#pragma unroll
    for (int i = 0; i < 32; ++i) {
        xy[2 + i] = (w00 * (double)f00[i] + w01 * (double)f01[i])
                  + (w10 * (double)f10[i] + w11 * (double)f11[i]);
    }

    double acc[64];
    {
        const double* b2d = wd + OFF_B2;
#pragma unroll
        for (int k = 0; k < 64; ++k) acc[k] = b2d[k];
        const double* W1d  = wd + OFF_W1;
        const double* W2Td = wd + OFF_W2T;
        const double* b1d  = wd + OFF_B1;
#pragma unroll 2
        for (int j = 0; j < 128; ++j) {
            const double* w1r = W1d + j * 34;
            double h0 = b1d[j], h1 = 0.0, h2 = 0.0, h3 = 0.0;
#pragma unroll
            for (int i = 0; i < 32; i += 4) {
                h0 = fma(xy[i + 0], w1r[i + 0], h0);
                h1 = fma(xy[i + 1], w1r[i + 1], h1);
                h2 = fma(xy[i + 2], w1r[i + 2], h2);
                h3 = fma(xy[i + 3], w1r[i + 3], h3);
            }
            h0 = fma(xy[32], w1r[32], h0);
            h1 = fma(xy[33], w1r[33], h1);
            double hj = (h0 + h2) + (h1 + h3);
            hj = fmax(hj, 0.0);
            const double* w2c = W2Td + j * 64;
#pragma unroll
            for (int k = 0; k < 64; ++k) acc[k] = fma(hj, w2c[k], acc[k]);
        }
#pragma unroll
        for (int k = 0; k < 64; ++k) acc[k] = fmax(acc[k], 0.0);
    }

    double accT[64];
    {
        const double t = (double)tf;
        const double* bs2d = wd + OFF_BS2;
#pragma unroll
        for (int k = 0; k < 64; ++k) accT[k] = bs2d[k];
        const double* Ws1d  = wd + OFF_WS1;
        const double* bs1d  = wd + OFF_BS1;
        const double* Ws2Td = wd + OFF_WS2T;
#pragma unroll 2
        for (int j = 0; j < 128; ++j) {
            double arg = 30.0 * fma(t, Ws1d[j], bs1d[j]);
            double htj = sin(arg);
            const double* wsc = Ws2Td + j * 64;
#pragma unroll
            for (int k = 0; k < 64; ++k) accT[k] = fma(htj, wsc[k], accT[k]);
        }
#pragma unroll
        for (int k = 0; k < 64; ++k) accT[k] = sin(accT[k]);
    }

    {
        const double* Wfd = wd + OFF_WF;
        const double* bfd = wd + OFF_BF;
#pragma unroll
        for (int k = 0; k < 64; ++k) {
            const double* wfr0 = Wfd + (size_t)k * 64;
            const double* wfr1 = Wfd + (size_t)(64 + k) * 64;
            double a0 = bfd[k],      a0b = 0.0;
            double a1 = bfd[64 + k], a1b = 0.0;
#pragma unroll
            for (int m = 0; m < 64; m += 2) {
                a0  = fma(accT[m + 0], wfr0[m + 0], a0);
                a0b = fma(accT[m + 1], wfr0[m + 1], a0b);
                a1  = fma(accT[m + 0], wfr1[m + 0], a1);
                a1b = fma(accT[m + 1], wfr1[m + 1], a1b);
            }
            double gk = tanh(a0 + a0b);
            double bk = tanh(a1 + a1b);
            acc[k] = fma(fma(0.1, gk, 1.0), acc[k], bk);
        }
    }

    double p[18];
    {
        const double* Whd = wd + OFF_WH;
        const double* bhd = wd + OFF_BH;
#pragma unroll
        for (int m = 0; m < 18; ++m) {
            const double* whr = Whd + m * 64;
            double s0 = bhd[m], s1 = 0.0, s2 = 0.0, s3 = 0.0;
#pragma unroll
            for (int k = 0; k < 64; k += 4) {
                s0 = fma(acc[k + 0], whr[k + 0], s0);
                s1 = fma(acc[k + 1], whr[k + 1], s1);
                s2 = fma(acc[k + 2], whr[k + 2], s2);
                s3 = fma(acc[k + 3], whr[k + 3], s3);
            }
            p[m] = (s0 + s2) + (s1 + s3);
        }
    }

    float o[18];
    {
        double l0 = p[0], l1 = p[6], l2 = p[12];
        double mx = fmax(l0, fmax(l1, l2));
        double e0 = exp(l0 - mx), e1 = exp(l1 - mx), e2 = exp(l2 - mx);
        double inv = 1.0 / (e0 + e1 + e2);
        o[0]  = (float)(e0 * inv);
        o[6]  = (float)(e1 * inv);
        o[12] = (float)(e2 * inv);
#pragma unroll
        for (int kk = 0; kk < 3; ++kk) {
            o[kk * 6 + 1] = (float)fmax(p[kk * 6 + 1], 0.0);
            double an = p[kk * 6 + 2];
            o[kk * 6 + 2] = (float)(an - floor(an / TWO_PI_D) * TWO_PI_D);
            double v1 = fmin(fmax(p[kk * 6 + 3], -10.0), 10.0);
            o[kk * 6 + 3] = (float)exp(v1);
            double v2 = fmin(fmax(p[kk * 6 + 4], -10.0), 10.0);
            o[kk * 6 + 4] = (float)exp(v2);
            o[kk * 6 + 5] = (float)(0.99 * tanh(p[kk * 6 + 5]));
        }
    }

    float* og = out + (size_t)n * 18;
#pragma unroll
    for (int i = 0; i < 18; i += 2)
        *reinterpret_cast<float2*>(og + i) = make_float2(o[i], o[i + 1]);
    float* oc = out + (size_t)18 * NPTS + (size_t)n * 3;
    oc[0] = xf; oc[1] = yf; oc[2] = tf;
}

// ---------------- fast f32 main pass with near-boundary flagging ----------------
__global__ __launch_bounds__(256) void main_f32(
    const float* __restrict__ coords, const float* __restrict__ grid,
    const float* __restrict__ W1, const float* __restrict__ b1,
    const float* __restrict__ b2, const float* __restrict__ Ws1,
    const float* __restrict__ bs1, const float* __restrict__ bs2,
    const float* __restrict__ Wf, const float* __restrict__ bf,
    const float* __restrict__ Wh, const float* __restrict__ bh,
    const float* __restrict__ W2T, const float* __restrict__ Ws2T,
    float* __restrict__ out, unsigned* __restrict__ cnt,
    unsigned* __restrict__ list, unsigned cap)
{
    int n = blockIdx.x * 256 + threadIdx.x;
    if (n >= NPTS) return;

    const float xf = coords[3 * n + 0];
    const float yf = coords[3 * n + 1];
    const float tf = coords[3 * n + 2];

    // bilinear (f32)
    float xi = (xf + 1.0f) * 0.5f * 63.0f;
    float yi = (yf + 1.0f) * 0.5f * 63.0f;
    int x0 = (int)floorf(xi); x0 = x0 < 0 ? 0 : (x0 > 62 ? 62 : x0);
    int y0 = (int)floorf(yi); y0 = y0 < 0 ? 0 : (y0 > 62 ? 62 : y0);
    float dx = xi - (float)x0;
    float dy = yi - (float)y0;
    float w00 = (1.0f - dx) * (1.0f - dy);
    float w01 = (1.0f - dx) * dy;
    float w10 = dx * (1.0f - dy);
    float w11 = dx * dy;

    const float* f00 = grid + ((size_t)y0 * 64 + x0) * 32;
    const float* f10 = f00 + 32;
    const float* f01 = f00 + 64 * 32;
    const float* f11 = f01 + 32;

    float xy[34];
    xy[0] = xf;
    xy[1] = yf;
#pragma unroll
    for (int i = 0; i < 32; ++i) {
        xy[2 + i] = fmaf(w00, f00[i], fmaf(w01, f01[i],
                    fmaf(w10, f10[i], w11 * f11[i])));
    }

    // stage A: h = relu(W1 xy + b1);  acc = relu(W2 h + b2)
    float acc[64];
#pragma unroll
    for (int k = 0; k < 64; ++k) acc[k] = b2[k];
#pragma unroll 2
    for (int j = 0; j < 128; ++j) {
        const float* w1r = W1 + j * 34;
        float h0 = b1[j], h1 = 0.0f, h2 = 0.0f, h3 = 0.0f;
#pragma unroll
        for (int i = 0; i < 32; i += 4) {
            h0 = fmaf(xy[i + 0], w1r[i + 0], h0);
            h1 = fmaf(xy[i + 1], w1r[i + 1], h1);
            h2 = fmaf(xy[i + 2], w1r[i + 2], h2);
            h3 = fmaf(xy[i + 3], w1r[i + 3], h3);
        }
        h0 = fmaf(xy[32], w1r[32], h0);
        h1 = fmaf(xy[33], w1r[33], h1);
        float hj = (h0 + h2) + (h1 + h3);
        hj = fmaxf(hj, 0.0f);
        const float* w2c = W2T + j * 64;
#pragma unroll
        for (int k = 0; k < 64; ++k) acc[k] = fmaf(hj, w2c[k], acc[k]);
    }
#pragma unroll
    for (int k = 0; k < 64; ++k) acc[k] = fmaxf(acc[k], 0.0f);

    // stage B: SIREN
    float accT[64];
#pragma unroll
    for (int k = 0; k < 64; ++k) accT[k] = bs2[k];
#pragma unroll 2
    for (int j = 0; j < 128; ++j) {
        float arg = 30.0f * fmaf(tf, Ws1[j], bs1[j]);
        float htj = sinf(arg);
        const float* wsc = Ws2T + j * 64;
#pragma unroll
        for (int k = 0; k < 64; ++k) accT[k] = fmaf(htj, wsc[k], accT[k]);
    }
#pragma unroll
    for (int k = 0; k < 64; ++k) accT[k] = sinf(accT[k]);

    // stage C: FiLM
#pragma unroll 2
    for (int k = 0; k < 64; ++k) {
        const float* wfr0 = Wf + (size_t)k * 64;
        const float* wfr1 = Wf + (size_t)(64 + k) * 64;
        float a0 = bf[k],      a0b = 0.0f;
        float a1 = bf[64 + k], a1b = 0.0f;
#pragma unroll
        for (int m = 0; m < 64; m += 2) {
            a0  = fmaf(accT[m + 0], wfr0[m + 0], a0);
            a0b = fmaf(accT[m + 1], wfr0[m + 1], a0b);
            a1  = fmaf(accT[m + 0], wfr1[m + 0], a1);
            a1b = fmaf(accT[m + 1], wfr1[m + 1], a1b);
        }
        float gk = tanhf(a0 + a0b);
        float bk = tanhf(a1 + a1b);
        acc[k] = fmaf(fmaf(0.1f, gk, 1.0f), acc[k], bk);
    }

    // stage D: head
    float p[18];
#pragma unroll
    for (int m = 0; m < 18; ++m) {
        const float* whr = Wh + m * 64;
        float s0 = bh[m], s1 = 0.0f, s2 = 0.0f, s3 = 0.0f;
#pragma unroll
        for (int k = 0; k < 64; k += 4) {
            s0 = fmaf(acc[k + 0], whr[k + 0], s0);
            s1 = fmaf(acc[k + 1], whr[k + 1], s1);
            s2 = fmaf(acc[k + 2], whr[k + 2], s2);
            s3 = fmaf(acc[k + 3], whr[k + 3], s3);
        }
        p[m] = (s0 + s2) + (s1 + s3);
    }

    // activations + boundary flag
    float o[18];
    bool flag = false;
    {
        float l0 = p[0], l1 = p[6], l2 = p[12];
        float mx = fmaxf(l0, fmaxf(l1, l2));
        float e0 = expf(l0 - mx), e1 = expf(l1 - mx), e2 = expf(l2 - mx);
        float inv = 1.0f / (e0 + e1 + e2);
        o[0]  = e0 * inv;
        o[6]  = e1 * inv;
        o[12] = e2 * inv;
#pragma unroll
        for (int kk = 0; kk < 3; ++kk) {
            o[kk * 6 + 1] = fmaxf(p[kk * 6 + 1], 0.0f);
            float an = p[kk * 6 + 2];
            float fl = floorf(an * (1.0f / TWO_PI_F));
            o[kk * 6 + 2] = an - fl * TWO_PI_F;
            // distance to nearest multiple of 2*pi
            float r = an - TWO_PI_F * rintf(an * (1.0f / TWO_PI_F));
            if (fabsf(r) < TAU_BOUND) flag = true;
            float v1 = fminf(fmaxf(p[kk * 6 + 3], -10.0f), 10.0f);
            o[kk * 6 + 3] = expf(v1);
            float v2 = fminf(fmaxf(p[kk * 6 + 4], -10.0f), 10.0f);
            o[kk * 6 + 4] = expf(v2);
            o[kk * 6 + 5] = 0.99f * tanhf(p[kk * 6 + 5]);
        }
    }

    float* og = out + (size_t)n * 18;
#pragma unroll
    for (int i = 0; i < 18; i += 2)
        *reinterpret_cast<float2*>(og + i) = make_float2(o[i], o[i + 1]);
    float* oc = out + (size_t)18 * NPTS + (size_t)n * 3;
    oc[0] = xf; oc[1] = yf; oc[2] = tf;

    if (flag) {
        unsigned idx = atomicAdd(cnt, 1u);
        if (idx < cap) list[idx] = (unsigned)n;
    }
}

// ---------------- f64 repair of flagged points ----------------
__global__ __launch_bounds__(64) void repair_f64(
    const float* __restrict__ coords, const float* __restrict__ grid,
    const double* __restrict__ wd, const unsigned* __restrict__ cnt,
    const unsigned* __restrict__ list, unsigned cap, float* __restrict__ out)
{
    unsigned total = *cnt;
    if (total > cap) total = cap;
    for (unsigned i = blockIdx.x * 64 + threadIdx.x; i < total;
         i += gridDim.x * 64) {
        point_f64((int)list[i], coords, grid, wd, out);
    }
}

// ---------------- fallback: all points in f64 (if ws too small) ----------------
__global__ __launch_bounds__(256) void full_f64(
    const float* __restrict__ coords, const float* __restrict__ grid,
    const double* __restrict__ wd, float* __restrict__ out)
{
    int n = blockIdx.x * 256 + threadIdx.x;
    if (n < NPTS) point_f64(n, coords, grid, wd, out);
}

extern "C" void kernel_launch(void* const* d_in, const int* in_sizes, int n_in,
                              void* d_out, int out_size, void* d_ws, size_t ws_size,
                              hipStream_t stream) {
    const float* coords = (const float*)d_in[0];
    const float* grid   = (const float*)d_in[1];
    const float* W1  = (const float*)d_in[2];
    const float* b1  = (const float*)d_in[3];
    const float* W2  = (const float*)d_in[4];
    const float* b2  = (const float*)d_in[5];
    const float* Ws1 = (const float*)d_in[6];
    const float* bs1 = (const float*)d_in[7];
    const float* Ws2 = (const float*)d_in[8];
    const float* bs2 = (const float*)d_in[9];
    const float* Wf  = (const float*)d_in[10];
    const float* bf  = (const float*)d_in[11];
    const float* Wh  = (const float*)d_in[12];
    const float* bh  = (const float*)d_in[13];
    char* ws = (char*)d_ws;
    double* wd = (double*)ws;
    float* out = (float*)d_out;

    prep_k<<<32, 256, 0, stream>>>(W1, b1, W2, b2, Ws1, bs1, Ws2, bs2,
                                   Wf, bf, Wh, bh, ws);

    if (ws_size < (size_t)WS_MIN_BYTES) {
        // not enough scratch for the repair list: proven-correct slow path
        full_f64<<<(NPTS + 255) / 256, 256, 0, stream>>>(coords, grid, wd, out);
        return;
    }

    float* W2T32  = (float*)(ws + W2T32_OFF);
    float* Ws2T32 = (float*)(ws + WS2T32_OFF);
    unsigned* cnt = (unsigned*)(ws + CNT_BYTE);
    unsigned* list = (unsigned*)(ws + LIST_BYTE);
    size_t cap_sz = (ws_size - (size_t)LIST_BYTE) / 4;
    unsigned cap = (cap_sz > (size_t)NPTS) ? (unsigned)NPTS : (unsigned)cap_sz;

    main_f32<<<(NPTS + 255) / 256, 256, 0, stream>>>(
        coords, grid, W1, b1, b2, Ws1, bs1, bs2, Wf, bf, Wh, bh,
        W2T32, Ws2T32, out, cnt, list, cap);

    repair_f64<<<256, 64, 0, stream>>>(coords, grid, wd, cnt, list, cap, out);
}